// Round 1
// baseline (4496.731 us; speedup 1.0000x reference)
//
#include <hip/hip_runtime.h>
#include <math.h>

#define NB   64      // batch
#define LL   196     // regions
#define AD   512     // image feat dim
#define HD   512     // hidden
#define VD   30000   // vocab
#define TS   20      // steps
#define G4   2048    // 4*H
#define NB5  469     // ceil(30000/64)

__device__ __forceinline__ float fast_tanh(float x) {
    float e = __builtin_exp2f(x * 2.8853900817779268f);   // exp(2x)
    return 1.0f - 2.0f / (e + 1.0f);
}
__device__ __forceinline__ float fast_sigmoid(float x) {
    return 1.0f / (1.0f + __builtin_exp2f(-x * 1.4426950408889634f));
}
__device__ __forceinline__ float fast_exp(float x) {
    return __builtin_exp2f(x * 1.4426950408889634f);
}

// ---------------- precompute: mean over L, h0/c0, tok init ----------------
__global__ void k_init(const float* __restrict__ hl, const float* __restrict__ Wh0,
                       const float* __restrict__ bh0, const float* __restrict__ Wc0,
                       const float* __restrict__ bc0, float* __restrict__ h_ws,
                       float* __restrict__ c_ws, int* __restrict__ tok_ws) {
    __shared__ float mean_s[AD];
    int n = blockIdx.x, tid = threadIdx.x;
    for (int a = tid; a < AD; a += 256) {
        float acc = 0.f;
        const float* p = hl + ((size_t)n * LL) * AD + a;
        for (int l = 0; l < LL; ++l) acc += p[(size_t)l * AD];
        mean_s[a] = acc / 196.0f;
    }
    __syncthreads();
    for (int hh = tid; hh < HD; hh += 256) {
        float ah = bh0[hh], ac = bc0[hh];
        for (int k = 0; k < AD; ++k) {
            float m = mean_s[k];
            ah = fmaf(m, Wh0[k * HD + hh], ah);
            ac = fmaf(m, Wc0[k * HD + hh], ac);
        }
        h_ws[n * HD + hh] = fast_tanh(ah);
        c_ws[n * HD + hh] = fast_tanh(ac);
    }
    if (tid == 0) tok_ws[n] = 1;  // START
}

// ---------------- precompute: hl_Wa = hl @ Wa  (12544x512 @ 512x512) ----------------
__global__ void k_hlwa(const float* __restrict__ Amat, const float* __restrict__ Bmat,
                       float* __restrict__ Cmat) {
    // A-tile stored transposed+skewed: element (k,m) at As[k][(m + (k&~3)) & 63]
    __shared__ __attribute__((aligned(16))) float As[16][64];
    __shared__ __attribute__((aligned(16))) float Bs[16][68];
    int tid = threadIdx.x;
    int m0 = blockIdx.x * 64, n0 = blockIdx.y * 64;
    int tx = tid & 15, ty = tid >> 4;
    int am = tid >> 2, ak4 = tid & 3;
    int bk = tid >> 4, bn4 = tid & 15;
    float acc[4][4] = {};
    for (int kt = 0; kt < 512; kt += 16) {
        float4 av = *(const float4*)&Amat[(size_t)(m0 + am) * 512 + kt + ak4 * 4];
        float4 bv = *(const float4*)&Bmat[(size_t)(kt + bk) * 512 + n0 + bn4 * 4];
        int acol = (am + ak4 * 4) & 63;
        As[ak4 * 4 + 0][acol] = av.x;
        As[ak4 * 4 + 1][acol] = av.y;
        As[ak4 * 4 + 2][acol] = av.z;
        As[ak4 * 4 + 3][acol] = av.w;
        *(float4*)&Bs[bk][bn4 * 4] = bv;
        __syncthreads();
#pragma unroll
        for (int k = 0; k < 16; ++k) {
            float4 a4 = *(const float4*)&As[k][(ty * 4 + (k & ~3)) & 63];
            float4 b4 = *(const float4*)&Bs[k][tx * 4];
            float avv[4] = {a4.x, a4.y, a4.z, a4.w};
            float bvv[4] = {b4.x, b4.y, b4.z, b4.w};
#pragma unroll
            for (int i = 0; i < 4; ++i)
#pragma unroll
                for (int j = 0; j < 4; ++j)
                    acc[i][j] = fmaf(avv[i], bvv[j], acc[i][j]);
        }
        __syncthreads();
    }
    for (int i = 0; i < 4; ++i) {
        float4 o = {acc[i][0], acc[i][1], acc[i][2], acc[i][3]};
        *(float4*)&Cmat[(size_t)(m0 + ty * 4 + i) * 512 + n0 + tx * 4] = o;
    }
}

// ---------------- per step: hUa = h@Ua + ba ; beta = sigmoid(h@Wb + bb) ----------------
__global__ void k_hua_beta(const float* __restrict__ h_ws, const float* __restrict__ Ua,
                           const float* __restrict__ ba, const float* __restrict__ Wb,
                           const float* __restrict__ bb, float* __restrict__ hUa_ws,
                           float* __restrict__ beta_ws) {
    __shared__ float hs[HD];
    __shared__ float red[256];
    int n = blockIdx.x, tid = threadIdx.x;
    for (int k = tid; k < HD; k += 256) hs[k] = h_ws[n * HD + k];
    __syncthreads();
    float bp = 0.f;
    for (int k = tid; k < HD; k += 256) bp += hs[k] * Wb[k];
    red[tid] = bp;
    for (int hh = tid; hh < HD; hh += 256) {
        float acc = ba[hh];
        for (int k = 0; k < HD; ++k) acc = fmaf(hs[k], Ua[k * HD + hh], acc);
        hUa_ws[n * HD + hh] = acc;
    }
    __syncthreads();
    for (int s = 128; s > 0; s >>= 1) {
        if (tid < s) red[tid] += red[tid + s];
        __syncthreads();
    }
    if (tid == 0) beta_ws[n] = fast_sigmoid(red[0] + bb[0]);
}

// ---------------- per step: e[n][l] = sum_h tanh(hlWa + hUa) * va ----------------
__global__ void k_att_e(const float* __restrict__ hlwa, const float* __restrict__ hUa_ws,
                        const float* __restrict__ va, float* __restrict__ e_ws) {
    int n = blockIdx.x >> 2, q = blockIdx.x & 3;
    int tid = threadIdx.x;
    int wave = tid >> 6, lane = tid & 63;
    float4 ua_a = *(const float4*)&hUa_ws[n * HD + lane * 4];
    float4 ua_b = *(const float4*)&hUa_ws[n * HD + 256 + lane * 4];
    float4 va_a = *(const float4*)&va[lane * 4];
    float4 va_b = *(const float4*)&va[256 + lane * 4];
    for (int ll = wave; ll < 49; ll += 4) {
        int l = q * 49 + ll;
        const float* base = hlwa + ((size_t)n * LL + l) * HD;
        float4 xa = *(const float4*)&base[lane * 4];
        float4 xb = *(const float4*)&base[256 + lane * 4];
        float s = 0.f;
        s = fmaf(fast_tanh(xa.x + ua_a.x), va_a.x, s);
        s = fmaf(fast_tanh(xa.y + ua_a.y), va_a.y, s);
        s = fmaf(fast_tanh(xa.z + ua_a.z), va_a.z, s);
        s = fmaf(fast_tanh(xa.w + ua_a.w), va_a.w, s);
        s = fmaf(fast_tanh(xb.x + ua_b.x), va_b.x, s);
        s = fmaf(fast_tanh(xb.y + ua_b.y), va_b.y, s);
        s = fmaf(fast_tanh(xb.z + ua_b.z), va_b.z, s);
        s = fmaf(fast_tanh(xb.w + ua_b.w), va_b.w, s);
        for (int m = 1; m < 64; m <<= 1) s += __shfl_xor(s, m, 64);
        if (lane == 0) e_ws[n * LL + l] = s;
    }
}

// ---------------- per step: softmax over L, z = (alpha @ hl) * beta ----------------
__global__ void k_soft_z(const float* __restrict__ e_ws, const float* __restrict__ hl,
                         const float* __restrict__ beta_ws, float* __restrict__ z_ws) {
    __shared__ float red[256];
    __shared__ float alpha[256];
    int n = blockIdx.x, tid = threadIdx.x;
    float ev = (tid < LL) ? e_ws[n * LL + tid] : -INFINITY;
    red[tid] = ev;
    __syncthreads();
    for (int s = 128; s > 0; s >>= 1) {
        if (tid < s) red[tid] = fmaxf(red[tid], red[tid + s]);
        __syncthreads();
    }
    float m = red[0];
    __syncthreads();
    float a = (tid < LL) ? fast_exp(ev - m) : 0.f;
    red[tid] = a;
    __syncthreads();
    for (int s = 128; s > 0; s >>= 1) {
        if (tid < s) red[tid] += red[tid + s];
        __syncthreads();
    }
    float sum = red[0];
    if (tid < LL) alpha[tid] = a / sum;
    __syncthreads();
    float beta = beta_ws[n];
    for (int a0 = tid; a0 < AD; a0 += 256) {
        float acc = 0.f;
        const float* p = hl + ((size_t)n * LL) * AD + a0;
        for (int l = 0; l < LL; ++l) acc = fmaf(alpha[l], p[(size_t)l * AD], acc);
        z_ws[n * AD + a0] = acc * beta;
    }
}

// ---------------- per step: gates partial GEMM  X[64x1536] @ W[1536x2048], K split 8 ----------------
__global__ void k_gates(const float* __restrict__ z_ws, const float* __restrict__ emb,
                        const int* __restrict__ tok_ws, const float* __restrict__ h_ws,
                        const float* __restrict__ Wx, const float* __restrict__ Wh,
                        float* __restrict__ gates_part) {
    __shared__ __attribute__((aligned(16))) float xt[64][64];  // (k_local, n) skewed
    int tid = threadIdx.x;
    int s = blockIdx.x & 7, jt = blockIdx.x >> 3;
    int j_l = tid & 63, q = tid >> 6;
    int j = jt * 64 + j_l;
    float acc[16] = {};
    for (int ch = 0; ch < 3; ++ch) {
        int kbase = s * 192 + ch * 64;
        __syncthreads();
        for (int it = 0; it < 4; ++it) {
            int nrow = (tid >> 4) + it * 16;
            int k4 = tid & 15;
            int gk = kbase + k4 * 4;
            const float* src;
            if (gk < 512)       src = &z_ws[nrow * 512 + gk];
            else if (gk < 1024) src = &emb[(size_t)tok_ws[nrow] * 512 + (gk - 512)];
            else                src = &h_ws[nrow * 512 + (gk - 1024)];
            float4 v = *(const float4*)src;
            int col = (nrow + k4 * 4) & 63;
            xt[k4 * 4 + 0][col] = v.x;
            xt[k4 * 4 + 1][col] = v.y;
            xt[k4 * 4 + 2][col] = v.z;
            xt[k4 * 4 + 3][col] = v.w;
        }
        __syncthreads();
        for (int kk = 0; kk < 64; ++kk) {
            int gk = kbase + kk;
            float w = (gk < 1024) ? Wx[(size_t)gk * G4 + j] : Wh[(size_t)(gk - 1024) * G4 + j];
            int cb = kk & ~3;
#pragma unroll
            for (int u = 0; u < 4; ++u) {
                float4 x4 = *(const float4*)&xt[kk][((q * 16 + u * 4) + cb) & 63];
                acc[u * 4 + 0] = fmaf(x4.x, w, acc[u * 4 + 0]);
                acc[u * 4 + 1] = fmaf(x4.y, w, acc[u * 4 + 1]);
                acc[u * 4 + 2] = fmaf(x4.z, w, acc[u * 4 + 2]);
                acc[u * 4 + 3] = fmaf(x4.w, w, acc[u * 4 + 3]);
            }
        }
    }
    float* gp = gates_part + (size_t)s * NB * G4;
    for (int i = 0; i < 16; ++i) {
        int m = q * 16 + i;
        gp[(size_t)m * G4 + j] = acc[i];
    }
}

// ---------------- per step: reduce gate partials + LSTM cell update ----------------
__global__ void k_lstm(const float* __restrict__ gates_part, const float* __restrict__ b_lstm,
                       float* __restrict__ h_ws, float* __restrict__ c_ws) {
    int idx = blockIdx.x * 256 + threadIdx.x;  // 0..32767
    int n = idx >> 9, hh = idx & 511;
    float ig = b_lstm[hh], fg = b_lstm[512 + hh], gg = b_lstm[1024 + hh], og = b_lstm[1536 + hh];
    for (int s = 0; s < 8; ++s) {
        const float* gp = gates_part + (size_t)s * NB * G4 + (size_t)n * G4;
        ig += gp[hh]; fg += gp[512 + hh]; gg += gp[1024 + hh]; og += gp[1536 + hh];
    }
    float c = c_ws[idx];
    float cn = fast_sigmoid(fg) * c + fast_sigmoid(ig) * fast_tanh(gg);
    float hn = fast_sigmoid(og) * fast_tanh(cn);
    c_ws[idx] = cn;
    h_ws[idx] = hn;
}

// ---------------- per step: logits = h @ Wout + bout, per-block argmax partials ----------------
__global__ void k_logits(const float* __restrict__ h_ws, const float* __restrict__ Wout,
                         const float* __restrict__ bout, float* __restrict__ pval,
                         int* __restrict__ pidx) {
    __shared__ __attribute__((aligned(16))) float smem[128 * 64];  // ht[128][64] skew; reused as vals[64][65]
    int tid = threadIdx.x;
    int j_l = tid & 63, q = tid >> 6;
    int j = blockIdx.x * 64 + j_l;
    int jc = j < VD ? j : VD - 1;
    float acc[16] = {};
    for (int ch = 0; ch < 4; ++ch) {
        int kbase = ch * 128;
        __syncthreads();
        for (int it = 0; it < 8; ++it) {
            int k4 = tid & 31;
            int nrow = (tid >> 5) + it * 8;
            float4 v = *(const float4*)&h_ws[nrow * 512 + kbase + k4 * 4];
            int col = (nrow + k4 * 4) & 63;
            smem[(k4 * 4 + 0) * 64 + col] = v.x;
            smem[(k4 * 4 + 1) * 64 + col] = v.y;
            smem[(k4 * 4 + 2) * 64 + col] = v.z;
            smem[(k4 * 4 + 3) * 64 + col] = v.w;
        }
        __syncthreads();
        for (int kk = 0; kk < 128; ++kk) {
            float w = Wout[(size_t)(kbase + kk) * VD + jc];
            int cb = kk & ~3;
#pragma unroll
            for (int u = 0; u < 4; ++u) {
                float4 x4 = *(const float4*)&smem[kk * 64 + (((q * 16 + u * 4) + cb) & 63)];
                acc[u * 4 + 0] = fmaf(x4.x, w, acc[u * 4 + 0]);
                acc[u * 4 + 1] = fmaf(x4.y, w, acc[u * 4 + 1]);
                acc[u * 4 + 2] = fmaf(x4.z, w, acc[u * 4 + 2]);
                acc[u * 4 + 3] = fmaf(x4.w, w, acc[u * 4 + 3]);
            }
        }
    }
    __syncthreads();
    float bj = bout[jc];
    bool jok = (j < VD);
    for (int i = 0; i < 16; ++i)
        smem[(q * 16 + i) * 65 + j_l] = jok ? (acc[i] + bj) : -INFINITY;
    __syncthreads();
    if (tid < 64) {
        int r = tid;
        float best = -INFINITY; int bi = 0;
        for (int jj = 0; jj < 64; ++jj) {
            float v = smem[r * 65 + jj];
            if (v > best) { best = v; bi = jj; }
        }
        pval[r * NB5 + blockIdx.x] = best;
        pidx[r * NB5 + blockIdx.x] = blockIdx.x * 64 + bi;
    }
}

// ---------------- per step: final argmax over block partials -> token ----------------
__global__ void k_argmax(const float* __restrict__ pval, const int* __restrict__ pidx,
                         int* __restrict__ tok_ws, int* __restrict__ out, int t) {
    int n = blockIdx.x, lane = threadIdx.x;
    float best = -INFINITY; int bi = 0x7fffffff;
    for (int b = lane; b < NB5; b += 64) {
        float v = pval[n * NB5 + b];
        int id = pidx[n * NB5 + b];
        if (v > best || (v == best && id < bi)) { best = v; bi = id; }
    }
    for (int m = 1; m < 64; m <<= 1) {
        float ov = __shfl_xor(best, m, 64);
        int oi = __shfl_xor(bi, m, 64);
        if (ov > best || (ov == best && oi < bi)) { best = ov; bi = oi; }
    }
    if (lane == 0) { tok_ws[n] = bi; out[n * TS + t] = bi; }
}

extern "C" void kernel_launch(void* const* d_in, const int* in_sizes, int n_in,
                              void* d_out, int out_size, void* d_ws, size_t ws_size,
                              hipStream_t stream) {
    const float* hl     = (const float*)d_in[0];
    const float* emb    = (const float*)d_in[1];
    const float* Wh0    = (const float*)d_in[2];
    const float* bh0    = (const float*)d_in[3];
    const float* Wc0    = (const float*)d_in[4];
    const float* bc0    = (const float*)d_in[5];
    const float* Wa     = (const float*)d_in[6];
    const float* Ua     = (const float*)d_in[7];
    const float* ba     = (const float*)d_in[8];
    const float* va     = (const float*)d_in[9];
    const float* Wb     = (const float*)d_in[10];
    const float* bb     = (const float*)d_in[11];
    const float* Wx     = (const float*)d_in[12];
    const float* Wh     = (const float*)d_in[13];
    const float* b_lstm = (const float*)d_in[14];
    const float* Wout   = (const float*)d_in[15];
    const float* bout   = (const float*)d_in[16];

    float* ws         = (float*)d_ws;
    float* hlwa       = ws;                          // 64*196*512 = 6422528
    float* h_ws       = ws + 6422528;                // 32768
    float* c_ws       = h_ws + 32768;
    float* hUa_ws     = c_ws + 32768;
    float* z_ws       = hUa_ws + 32768;
    float* e_ws       = z_ws + 32768;                // 12544
    float* beta_ws    = e_ws + 12544;                // 64
    int*   tok_ws     = (int*)(beta_ws + 64);        // 64
    float* gates_part = beta_ws + 128;               // 8*64*2048 = 1048576
    float* pval       = gates_part + 8 * 64 * 2048;  // 64*469
    int*   pidx       = (int*)(pval + 64 * NB5);     // 64*469
    int*   out        = (int*)d_out;

    k_init<<<64, 256, 0, stream>>>(hl, Wh0, bh0, Wc0, bc0, h_ws, c_ws, tok_ws);
    k_hlwa<<<dim3(196, 8), 256, 0, stream>>>(hl, Wa, hlwa);
    for (int t = 0; t < TS; ++t) {
        k_hua_beta<<<64, 256, 0, stream>>>(h_ws, Ua, ba, Wb, bb, hUa_ws, beta_ws);
        k_att_e<<<256, 256, 0, stream>>>(hlwa, hUa_ws, va, e_ws);
        k_soft_z<<<64, 256, 0, stream>>>(e_ws, hl, beta_ws, z_ws);
        k_gates<<<256, 256, 0, stream>>>(z_ws, emb, tok_ws, h_ws, Wx, Wh, gates_part);
        k_lstm<<<128, 256, 0, stream>>>(gates_part, b_lstm, h_ws, c_ws);
        k_logits<<<NB5, 256, 0, stream>>>(h_ws, Wout, bout, pval, pidx);
        k_argmax<<<64, 64, 0, stream>>>(pval, pidx, tok_ws, out, t);
    }
}

// Round 2
// 4345.736 us; speedup vs baseline: 1.0347x; 1.0347x over previous
//
#include <hip/hip_runtime.h>
#include <math.h>

#define NB   64      // batch
#define LL   196     // regions
#define AD   512     // image feat dim
#define HD   512     // hidden
#define VD   30000   // vocab
#define TS   20      // steps
#define G4   2048    // 4*H
#define NB5  469     // ceil(30000/64)

__device__ __forceinline__ float fast_tanh(float x) {
    float e = __builtin_exp2f(x * 2.8853900817779268f);   // exp(2x)
    return 1.0f - 2.0f / (e + 1.0f);
}
__device__ __forceinline__ float fast_sigmoid(float x) {
    return 1.0f / (1.0f + __builtin_exp2f(-x * 1.4426950408889634f));
}
__device__ __forceinline__ float fast_exp(float x) {
    return __builtin_exp2f(x * 1.4426950408889634f);
}

// ---------------- precompute: mean over L, h0/c0, tok init ----------------
__global__ void k_init(const float* __restrict__ hl, const float* __restrict__ Wh0,
                       const float* __restrict__ bh0, const float* __restrict__ Wc0,
                       const float* __restrict__ bc0, float* __restrict__ h_ws,
                       float* __restrict__ c_ws, int* __restrict__ tok_ws) {
    __shared__ float mean_s[AD];
    int n = blockIdx.x, tid = threadIdx.x;
    for (int a = tid; a < AD; a += 256) {
        float acc = 0.f;
        const float* p = hl + ((size_t)n * LL) * AD + a;
        for (int l = 0; l < LL; ++l) acc += p[(size_t)l * AD];
        mean_s[a] = acc / 196.0f;
    }
    __syncthreads();
    for (int hh = tid; hh < HD; hh += 256) {
        float ah = bh0[hh], ac = bc0[hh];
        for (int k = 0; k < AD; ++k) {
            float m = mean_s[k];
            ah = fmaf(m, Wh0[k * HD + hh], ah);
            ac = fmaf(m, Wc0[k * HD + hh], ac);
        }
        h_ws[n * HD + hh] = fast_tanh(ah);
        c_ws[n * HD + hh] = fast_tanh(ac);
    }
    if (tid == 0) tok_ws[n] = 1;  // START
}

// ---------------- precompute: hl_Wa = hl @ Wa  (12544x512 @ 512x512) ----------------
// outer-product pattern: thread = 4 rows x 4 cols; per k: 1 ds_read_b128 + 1 dwordx4
__global__ void k_hlwa(const float* __restrict__ Amat, const float* __restrict__ Bmat,
                       float* __restrict__ Cmat) {
    __shared__ __attribute__((aligned(16))) float xt[64 * 64];  // (k, m) skewed
    int tid = threadIdx.x;
    int lane16 = tid & 15, rowg = tid >> 4;
    int m0 = blockIdx.x * 64, jb = blockIdx.y * 64;
    float acc[4][4] = {};
    for (int ch = 0; ch < 8; ++ch) {
        int kbase = ch * 64;
        __syncthreads();
        for (int it = 0; it < 4; ++it) {
            int k4 = tid & 15;
            int nrow = (tid >> 4) + it * 16;
            float4 v = *(const float4*)&Amat[(size_t)(m0 + nrow) * 512 + kbase + k4 * 4];
            int col = (nrow + k4 * 4) & 63;
            xt[(k4 * 4 + 0) * 64 + col] = v.x;
            xt[(k4 * 4 + 1) * 64 + col] = v.y;
            xt[(k4 * 4 + 2) * 64 + col] = v.z;
            xt[(k4 * 4 + 3) * 64 + col] = v.w;
        }
        __syncthreads();
#pragma unroll 8
        for (int kk = 0; kk < 64; ++kk) {
            float4 w4 = *(const float4*)&Bmat[(size_t)(kbase + kk) * 512 + jb + lane16 * 4];
            float4 h4 = *(const float4*)&xt[kk * 64 + ((rowg * 4 + (kk & ~3)) & 63)];
            float hv[4] = {h4.x, h4.y, h4.z, h4.w};
            float wv[4] = {w4.x, w4.y, w4.z, w4.w};
#pragma unroll
            for (int r = 0; r < 4; ++r)
#pragma unroll
                for (int j = 0; j < 4; ++j) acc[r][j] = fmaf(hv[r], wv[j], acc[r][j]);
        }
    }
    for (int r = 0; r < 4; ++r) {
        float4 o = {acc[r][0], acc[r][1], acc[r][2], acc[r][3]};
        *(float4*)&Cmat[(size_t)(m0 + rowg * 4 + r) * 512 + jb + lane16 * 4] = o;
    }
}

// ---------------- per step: hua_part[s] = h @ Ua[kslice]  (K-split 8) ----------------
__global__ void k_hua(const float* __restrict__ h_ws, const float* __restrict__ Ua,
                      float* __restrict__ hua_part) {
    __shared__ __attribute__((aligned(16))) float xt[64 * 64];
    int tid = threadIdx.x;
    int lane16 = tid & 15, rowg = tid >> 4;
    int s = blockIdx.x & 7, jt = blockIdx.x >> 3;
    int jb = jt * 64, kbase = s * 64;
    float acc[4][4] = {};
    for (int it = 0; it < 4; ++it) {
        int k4 = tid & 15;
        int nrow = (tid >> 4) + it * 16;
        float4 v = *(const float4*)&h_ws[nrow * 512 + kbase + k4 * 4];
        int col = (nrow + k4 * 4) & 63;
        xt[(k4 * 4 + 0) * 64 + col] = v.x;
        xt[(k4 * 4 + 1) * 64 + col] = v.y;
        xt[(k4 * 4 + 2) * 64 + col] = v.z;
        xt[(k4 * 4 + 3) * 64 + col] = v.w;
    }
    __syncthreads();
#pragma unroll 8
    for (int kk = 0; kk < 64; ++kk) {
        float4 w4 = *(const float4*)&Ua[(size_t)(kbase + kk) * 512 + jb + lane16 * 4];
        float4 h4 = *(const float4*)&xt[kk * 64 + ((rowg * 4 + (kk & ~3)) & 63)];
        float hv[4] = {h4.x, h4.y, h4.z, h4.w};
        float wv[4] = {w4.x, w4.y, w4.z, w4.w};
#pragma unroll
        for (int r = 0; r < 4; ++r)
#pragma unroll
            for (int j = 0; j < 4; ++j) acc[r][j] = fmaf(hv[r], wv[j], acc[r][j]);
    }
    float* gp = hua_part + (size_t)s * NB * HD;
    for (int r = 0; r < 4; ++r) {
        float4 o = {acc[r][0], acc[r][1], acc[r][2], acc[r][3]};
        *(float4*)&gp[(size_t)(rowg * 4 + r) * 512 + jb + lane16 * 4] = o;
    }
}

// ---------------- per step: e[n][l] = sum_h tanh(hlWa + hUa + ba) * va ----------------
__global__ void k_att_e(const float* __restrict__ hlwa, const float* __restrict__ hua_part,
                        const float* __restrict__ ba, const float* __restrict__ va,
                        float* __restrict__ e_ws) {
    int n = blockIdx.x >> 2, q = blockIdx.x & 3;
    int tid = threadIdx.x;
    int wave = tid >> 6, lane = tid & 63;
    float4 ua_a = *(const float4*)&ba[lane * 4];
    float4 ua_b = *(const float4*)&ba[256 + lane * 4];
    for (int s = 0; s < 8; ++s) {
        const float* p = hua_part + (size_t)s * NB * HD + n * HD;
        float4 pa = *(const float4*)&p[lane * 4];
        float4 pb = *(const float4*)&p[256 + lane * 4];
        ua_a.x += pa.x; ua_a.y += pa.y; ua_a.z += pa.z; ua_a.w += pa.w;
        ua_b.x += pb.x; ua_b.y += pb.y; ua_b.z += pb.z; ua_b.w += pb.w;
    }
    float4 va_a = *(const float4*)&va[lane * 4];
    float4 va_b = *(const float4*)&va[256 + lane * 4];
    for (int ll = wave; ll < 49; ll += 4) {
        int l = q * 49 + ll;
        const float* base = hlwa + ((size_t)n * LL + l) * HD;
        float4 xa = *(const float4*)&base[lane * 4];
        float4 xb = *(const float4*)&base[256 + lane * 4];
        float s = 0.f;
        s = fmaf(fast_tanh(xa.x + ua_a.x), va_a.x, s);
        s = fmaf(fast_tanh(xa.y + ua_a.y), va_a.y, s);
        s = fmaf(fast_tanh(xa.z + ua_a.z), va_a.z, s);
        s = fmaf(fast_tanh(xa.w + ua_a.w), va_a.w, s);
        s = fmaf(fast_tanh(xb.x + ua_b.x), va_b.x, s);
        s = fmaf(fast_tanh(xb.y + ua_b.y), va_b.y, s);
        s = fmaf(fast_tanh(xb.z + ua_b.z), va_b.z, s);
        s = fmaf(fast_tanh(xb.w + ua_b.w), va_b.w, s);
        for (int m = 1; m < 64; m <<= 1) s += __shfl_xor(s, m, 64);
        if (lane == 0) e_ws[n * LL + l] = s;
    }
}

// ---------------- per step: softmax over L, beta gate, z = (alpha @ hl) * beta ----------------
__global__ void k_soft_z(const float* __restrict__ e_ws, const float* __restrict__ hl,
                         const float* __restrict__ h_ws, const float* __restrict__ Wb,
                         const float* __restrict__ bb, float* __restrict__ z_ws) {
    __shared__ float red[256];
    __shared__ float alpha[256];
    __shared__ float zs[512];
    __shared__ float beta_s;
    int n = blockIdx.x, tid = threadIdx.x;
    float ev = (tid < LL) ? e_ws[n * LL + tid] : -INFINITY;
    red[tid] = ev;
    __syncthreads();
    for (int s = 128; s > 0; s >>= 1) {
        if (tid < s) red[tid] = fmaxf(red[tid], red[tid + s]);
        __syncthreads();
    }
    float m = red[0];
    __syncthreads();
    float a = (tid < LL) ? fast_exp(ev - m) : 0.f;
    red[tid] = a;
    __syncthreads();
    for (int s = 128; s > 0; s >>= 1) {
        if (tid < s) red[tid] += red[tid + s];
        __syncthreads();
    }
    float sum = red[0];
    alpha[tid] = a / sum;
    __syncthreads();
    // beta = sigmoid(h . Wb + bb)
    float bp = h_ws[n * HD + tid] * Wb[tid] + h_ws[n * HD + 256 + tid] * Wb[256 + tid];
    red[tid] = bp;
    __syncthreads();
    for (int s = 128; s > 0; s >>= 1) {
        if (tid < s) red[tid] += red[tid + s];
        __syncthreads();
    }
    if (tid == 0) beta_s = fast_sigmoid(red[0] + bb[0]);
    // z: 128 a-quads, 2 l-halves
    int lq = tid >> 7, ai = tid & 127;
    const float* base = hl + ((size_t)n * LL) * AD + ai * 4;
    float4 acc4 = {0.f, 0.f, 0.f, 0.f};
    int l0 = lq * 98, l1 = l0 + 98;
    for (int l = l0; l < l1; ++l) {
        float al = alpha[l];
        float4 v = *(const float4*)&base[(size_t)l * AD];
        acc4.x = fmaf(al, v.x, acc4.x);
        acc4.y = fmaf(al, v.y, acc4.y);
        acc4.z = fmaf(al, v.z, acc4.z);
        acc4.w = fmaf(al, v.w, acc4.w);
    }
    if (lq == 1) *(float4*)&zs[ai * 4] = acc4;
    __syncthreads();
    if (lq == 0) {
        float4 o = *(const float4*)&zs[ai * 4];
        float b = beta_s;
        o.x = (o.x + acc4.x) * b;
        o.y = (o.y + acc4.y) * b;
        o.z = (o.z + acc4.z) * b;
        o.w = (o.w + acc4.w) * b;
        *(float4*)&z_ws[n * AD + ai * 4] = o;
    }
}

// ---------------- per step: gates partial GEMM  X[64x1536] @ W[1536x2048], K split 8 ----------------
__global__ void k_gates(const float* __restrict__ z_ws, const float* __restrict__ emb,
                        const int* __restrict__ tok_ws, const float* __restrict__ h_ws,
                        const float* __restrict__ Wx, const float* __restrict__ Wh,
                        float* __restrict__ gates_part) {
    __shared__ __attribute__((aligned(16))) float xt[64 * 64];
    int tid = threadIdx.x;
    int lane16 = tid & 15, rowg = tid >> 4;
    int s = blockIdx.x & 7, jt = blockIdx.x >> 3;
    int jb = jt * 64;
    float acc[4][4] = {};
    for (int ch = 0; ch < 3; ++ch) {
        int kbase = s * 192 + ch * 64;
        __syncthreads();
        for (int it = 0; it < 4; ++it) {
            int nrow = (tid >> 4) + it * 16;
            int k4 = tid & 15;
            int gk = kbase + k4 * 4;
            const float* src;
            if (gk < 512)       src = &z_ws[nrow * 512 + gk];
            else if (gk < 1024) src = &emb[(size_t)tok_ws[nrow] * 512 + (gk - 512)];
            else                src = &h_ws[nrow * 512 + (gk - 1024)];
            float4 v = *(const float4*)src;
            int col = (nrow + k4 * 4) & 63;
            xt[(k4 * 4 + 0) * 64 + col] = v.x;
            xt[(k4 * 4 + 1) * 64 + col] = v.y;
            xt[(k4 * 4 + 2) * 64 + col] = v.z;
            xt[(k4 * 4 + 3) * 64 + col] = v.w;
        }
        __syncthreads();
#pragma unroll 8
        for (int kk = 0; kk < 64; ++kk) {
            int gk = kbase + kk;
            const float* wrow = (gk < 1024) ? &Wx[(size_t)gk * G4] : &Wh[(size_t)(gk - 1024) * G4];
            float4 w4 = *(const float4*)&wrow[jb + lane16 * 4];
            float4 h4 = *(const float4*)&xt[kk * 64 + ((rowg * 4 + (kk & ~3)) & 63)];
            float hv[4] = {h4.x, h4.y, h4.z, h4.w};
            float wv[4] = {w4.x, w4.y, w4.z, w4.w};
#pragma unroll
            for (int r = 0; r < 4; ++r)
#pragma unroll
                for (int j = 0; j < 4; ++j) acc[r][j] = fmaf(hv[r], wv[j], acc[r][j]);
        }
    }
    float* gp = gates_part + (size_t)s * NB * G4;
    for (int r = 0; r < 4; ++r) {
        float4 o = {acc[r][0], acc[r][1], acc[r][2], acc[r][3]};
        *(float4*)&gp[(size_t)(rowg * 4 + r) * G4 + jb + lane16 * 4] = o;
    }
}

// ---------------- per step: reduce gate partials + LSTM cell update ----------------
__global__ void k_lstm(const float* __restrict__ gates_part, const float* __restrict__ b_lstm,
                       float* __restrict__ h_ws, float* __restrict__ c_ws) {
    int idx = blockIdx.x * 256 + threadIdx.x;  // 0..32767
    int n = idx >> 9, hh = idx & 511;
    float ig = b_lstm[hh], fg = b_lstm[512 + hh], gg = b_lstm[1024 + hh], og = b_lstm[1536 + hh];
    for (int s = 0; s < 8; ++s) {
        const float* gp = gates_part + (size_t)s * NB * G4 + (size_t)n * G4;
        ig += gp[hh]; fg += gp[512 + hh]; gg += gp[1024 + hh]; og += gp[1536 + hh];
    }
    float c = c_ws[idx];
    float cn = fast_sigmoid(fg) * c + fast_sigmoid(ig) * fast_tanh(gg);
    float hn = fast_sigmoid(og) * fast_tanh(cn);
    c_ws[idx] = cn;
    h_ws[idx] = hn;
}

// ---------------- per step: logits = h @ Wout + bout, per-block argmax partials ----------------
__global__ void k_logits(const float* __restrict__ h_ws, const float* __restrict__ Wout,
                         const float* __restrict__ bout, float* __restrict__ pval,
                         int* __restrict__ pidx) {
    __shared__ __attribute__((aligned(16))) float smem[128 * 64];  // ht chunk; reused for argmax
    int tid = threadIdx.x;
    int lane16 = tid & 15, rowg = tid >> 4;
    int jb = blockIdx.x * 64;
    int j0 = jb + lane16 * 4;
    bool jok = (j0 + 4 <= VD);
    int jc0 = jok ? j0 : (VD - 4);
    float acc[4][4] = {};
    for (int ch = 0; ch < 4; ++ch) {
        int kbase = ch * 128;
        __syncthreads();
        for (int it = 0; it < 8; ++it) {
            int k4 = tid & 31;
            int nrow = (tid >> 5) + it * 8;
            float4 v = *(const float4*)&h_ws[nrow * 512 + kbase + k4 * 4];
            int col = (nrow + k4 * 4) & 63;
            smem[(k4 * 4 + 0) * 64 + col] = v.x;
            smem[(k4 * 4 + 1) * 64 + col] = v.y;
            smem[(k4 * 4 + 2) * 64 + col] = v.z;
            smem[(k4 * 4 + 3) * 64 + col] = v.w;
        }
        __syncthreads();
#pragma unroll 8
        for (int kk = 0; kk < 128; ++kk) {
            float4 w4 = *(const float4*)&Wout[(size_t)(kbase + kk) * VD + jc0];
            float4 h4 = *(const float4*)&smem[kk * 64 + ((rowg * 4 + (kk & ~3)) & 63)];
            float hv[4] = {h4.x, h4.y, h4.z, h4.w};
            float wv[4] = {w4.x, w4.y, w4.z, w4.w};
#pragma unroll
            for (int r = 0; r < 4; ++r)
#pragma unroll
                for (int j = 0; j < 4; ++j) acc[r][j] = fmaf(hv[r], wv[j], acc[r][j]);
        }
    }
    __syncthreads();
    float4 b4 = *(const float4*)&bout[jc0];
    float bv[4] = {b4.x, b4.y, b4.z, b4.w};
    float* vs = smem;                 // [64][16]
    int* is = (int*)(smem + 1024);    // [64][16]
    for (int r = 0; r < 4; ++r) {
        float best = -INFINITY;
        int bi = 0x7fffffff;
        for (int j = 0; j < 4; ++j) {
            float v = jok ? (acc[r][j] + bv[j]) : -INFINITY;
            if (v > best) { best = v; bi = j0 + j; }
        }
        vs[(rowg * 4 + r) * 16 + lane16] = best;
        is[(rowg * 4 + r) * 16 + lane16] = bi;
    }
    __syncthreads();
    if (tid < 64) {
        float best = -INFINITY;
        int bi = 0x7fffffff;
        for (int c = 0; c < 16; ++c) {
            float v = vs[tid * 16 + c];
            int id = is[tid * 16 + c];
            if (v > best || (v == best && id < bi)) { best = v; bi = id; }
        }
        pval[tid * NB5 + blockIdx.x] = best;
        pidx[tid * NB5 + blockIdx.x] = bi;
    }
}

// ---------------- per step: final argmax over block partials -> token ----------------
__global__ void k_argmax(const float* __restrict__ pval, const int* __restrict__ pidx,
                         int* __restrict__ tok_ws, int* __restrict__ out, int t) {
    int n = blockIdx.x, lane = threadIdx.x;
    float best = -INFINITY; int bi = 0x7fffffff;
    for (int b = lane; b < NB5; b += 64) {
        float v = pval[n * NB5 + b];
        int id = pidx[n * NB5 + b];
        if (v > best || (v == best && id < bi)) { best = v; bi = id; }
    }
    for (int m = 1; m < 64; m <<= 1) {
        float ov = __shfl_xor(best, m, 64);
        int oi = __shfl_xor(bi, m, 64);
        if (ov > best || (ov == best && oi < bi)) { best = ov; bi = oi; }
    }
    if (lane == 0) { tok_ws[n] = bi; out[n * TS + t] = bi; }
}

extern "C" void kernel_launch(void* const* d_in, const int* in_sizes, int n_in,
                              void* d_out, int out_size, void* d_ws, size_t ws_size,
                              hipStream_t stream) {
    const float* hl     = (const float*)d_in[0];
    const float* emb    = (const float*)d_in[1];
    const float* Wh0    = (const float*)d_in[2];
    const float* bh0    = (const float*)d_in[3];
    const float* Wc0    = (const float*)d_in[4];
    const float* bc0    = (const float*)d_in[5];
    const float* Wa     = (const float*)d_in[6];
    const float* Ua     = (const float*)d_in[7];
    const float* ba     = (const float*)d_in[8];
    const float* va     = (const float*)d_in[9];
    const float* Wb     = (const float*)d_in[10];
    const float* bb     = (const float*)d_in[11];
    const float* Wx     = (const float*)d_in[12];
    const float* Wh     = (const float*)d_in[13];
    const float* b_lstm = (const float*)d_in[14];
    const float* Wout   = (const float*)d_in[15];
    const float* bout   = (const float*)d_in[16];

    float* ws         = (float*)d_ws;
    float* hlwa       = ws;                          // 6422528
    float* h_ws       = ws + 6422528;                // 32768
    float* c_ws       = h_ws + 32768;                // 32768
    float* z_ws       = c_ws + 32768;                // 32768
    float* e_ws       = z_ws + 32768;                // 12544
    int*   tok_ws     = (int*)(e_ws + 12544);        // 64
    float* hua_part   = e_ws + 12544 + 64;           // 8*64*512 = 262144
    float* gates_part = hua_part + 262144;           // 8*64*2048 = 1048576
    float* pval       = gates_part + 1048576;        // 64*469
    int*   pidx       = (int*)(pval + 64 * NB5);     // 64*469
    int*   out        = (int*)d_out;

    k_init<<<64, 256, 0, stream>>>(hl, Wh0, bh0, Wc0, bc0, h_ws, c_ws, tok_ws);
    k_hlwa<<<dim3(196, 8), 256, 0, stream>>>(hl, Wa, hlwa);
    for (int t = 0; t < TS; ++t) {
        k_hua<<<64, 256, 0, stream>>>(h_ws, Ua, hua_part);
        k_att_e<<<256, 256, 0, stream>>>(hlwa, hua_part, ba, va, e_ws);
        k_soft_z<<<64, 256, 0, stream>>>(e_ws, hl, h_ws, Wb, bb, z_ws);
        k_gates<<<256, 256, 0, stream>>>(z_ws, emb, tok_ws, h_ws, Wx, Wh, gates_part);
        k_lstm<<<128, 256, 0, stream>>>(gates_part, b_lstm, h_ws, c_ws);
        k_logits<<<NB5, 256, 0, stream>>>(h_ws, Wout, bout, pval, pidx);
        k_argmax<<<64, 64, 0, stream>>>(pval, pidx, tok_ws, out, t);
    }
}

// Round 3
// 2467.131 us; speedup vs baseline: 1.8227x; 1.7615x over previous
//
#include <hip/hip_runtime.h>
#include <math.h>

#define NB   64      // batch
#define LL   196     // regions
#define AD   512     // image feat dim
#define HD   512     // hidden
#define VD   30000   // vocab
#define TS   20      // steps
#define G4   2048    // 4*H
#define NB5  469     // ceil(30000/64)

__device__ __forceinline__ float fast_tanh(float x) {
    float e = __builtin_exp2f(x * 2.8853900817779268f);   // exp(2x)
    return 1.0f - 2.0f / (e + 1.0f);
}
__device__ __forceinline__ float fast_sigmoid(float x) {
    return 1.0f / (1.0f + __builtin_exp2f(-x * 1.4426950408889634f));
}
__device__ __forceinline__ float fast_exp(float x) {
    return __builtin_exp2f(x * 1.4426950408889634f);
}

// async global->LDS DMA, 16B per lane; lds base must be wave-uniform
__device__ __forceinline__ void gload_lds16(const void* g, void* l) {
    __builtin_amdgcn_global_load_lds((const __attribute__((address_space(1))) void*)g,
                                     (__attribute__((address_space(3))) void*)l, 16, 0, 0);
}

// ---------------- precompute: mean over L, h0/c0, tok init ----------------
__global__ void k_init(const float* __restrict__ hl, const float* __restrict__ Wh0,
                       const float* __restrict__ bh0, const float* __restrict__ Wc0,
                       const float* __restrict__ bc0, float* __restrict__ h_ws,
                       float* __restrict__ c_ws, int* __restrict__ tok_ws) {
    __shared__ float mean_s[AD];
    int n = blockIdx.x, tid = threadIdx.x;
    for (int a = tid; a < AD; a += 256) {
        float acc = 0.f;
        const float* p = hl + ((size_t)n * LL) * AD + a;
        for (int l = 0; l < LL; ++l) acc += p[(size_t)l * AD];
        mean_s[a] = acc / 196.0f;
    }
    __syncthreads();
    for (int hh = tid; hh < HD; hh += 256) {
        float ah = bh0[hh], ac = bc0[hh];
        for (int k = 0; k < AD; ++k) {
            float m = mean_s[k];
            ah = fmaf(m, Wh0[k * HD + hh], ah);
            ac = fmaf(m, Wc0[k * HD + hh], ac);
        }
        h_ws[n * HD + hh] = fast_tanh(ah);
        c_ws[n * HD + hh] = fast_tanh(ac);
    }
    if (tid == 0) tok_ws[n] = 1;  // START
}

// ---------------- precompute: hl_Wa = hl @ Wa  (12544x512 @ 512x512) ----------------
__global__ void k_hlwa(const float* __restrict__ Amat, const float* __restrict__ Bmat,
                       float* __restrict__ Cmat) {
    __shared__ __attribute__((aligned(16))) float xt[64 * 64];  // (k, m) skewed
    int tid = threadIdx.x;
    int lane16 = tid & 15, rowg = tid >> 4;
    int m0 = blockIdx.x * 64, jb = blockIdx.y * 64;
    float acc[4][4] = {};
    for (int ch = 0; ch < 8; ++ch) {
        int kbase = ch * 64;
        __syncthreads();
        for (int it = 0; it < 4; ++it) {
            int k4 = tid & 15;
            int nrow = (tid >> 4) + it * 16;
            float4 v = *(const float4*)&Amat[(size_t)(m0 + nrow) * 512 + kbase + k4 * 4];
            int col = (nrow + k4 * 4) & 63;
            xt[(k4 * 4 + 0) * 64 + col] = v.x;
            xt[(k4 * 4 + 1) * 64 + col] = v.y;
            xt[(k4 * 4 + 2) * 64 + col] = v.z;
            xt[(k4 * 4 + 3) * 64 + col] = v.w;
        }
        __syncthreads();
#pragma unroll 8
        for (int kk = 0; kk < 64; ++kk) {
            float4 w4 = *(const float4*)&Bmat[(size_t)(kbase + kk) * 512 + jb + lane16 * 4];
            float4 h4 = *(const float4*)&xt[kk * 64 + ((rowg * 4 + (kk & ~3)) & 63)];
            float hv[4] = {h4.x, h4.y, h4.z, h4.w};
            float wv[4] = {w4.x, w4.y, w4.z, w4.w};
#pragma unroll
            for (int r = 0; r < 4; ++r)
#pragma unroll
                for (int j = 0; j < 4; ++j) acc[r][j] = fmaf(hv[r], wv[j], acc[r][j]);
        }
    }
    for (int r = 0; r < 4; ++r) {
        float4 o = {acc[r][0], acc[r][1], acc[r][2], acc[r][3]};
        *(float4*)&Cmat[(size_t)(m0 + rowg * 4 + r) * 512 + jb + lane16 * 4] = o;
    }
}

// ---------------- per step: hua_part[s] = h @ Ua[kslice]  (K-split 8) ----------------
__global__ void k_hua(const float* __restrict__ h_ws, const float* __restrict__ Ua,
                      float* __restrict__ hua_part) {
    __shared__ __attribute__((aligned(16))) float xt[64 * 64];
    int tid = threadIdx.x;
    int lane16 = tid & 15, rowg = tid >> 4;
    int s = blockIdx.x & 7, jt = blockIdx.x >> 3;
    int jb = jt * 64, kbase = s * 64;
    float acc[4][4] = {};
    for (int it = 0; it < 4; ++it) {
        int k4 = tid & 15;
        int nrow = (tid >> 4) + it * 16;
        float4 v = *(const float4*)&h_ws[nrow * 512 + kbase + k4 * 4];
        int col = (nrow + k4 * 4) & 63;
        xt[(k4 * 4 + 0) * 64 + col] = v.x;
        xt[(k4 * 4 + 1) * 64 + col] = v.y;
        xt[(k4 * 4 + 2) * 64 + col] = v.z;
        xt[(k4 * 4 + 3) * 64 + col] = v.w;
    }
    __syncthreads();
#pragma unroll 8
    for (int kk = 0; kk < 64; ++kk) {
        float4 w4 = *(const float4*)&Ua[(size_t)(kbase + kk) * 512 + jb + lane16 * 4];
        float4 h4 = *(const float4*)&xt[kk * 64 + ((rowg * 4 + (kk & ~3)) & 63)];
        float hv[4] = {h4.x, h4.y, h4.z, h4.w};
        float wv[4] = {w4.x, w4.y, w4.z, w4.w};
#pragma unroll
        for (int r = 0; r < 4; ++r)
#pragma unroll
            for (int j = 0; j < 4; ++j) acc[r][j] = fmaf(hv[r], wv[j], acc[r][j]);
    }
    float* gp = hua_part + (size_t)s * NB * HD;
    for (int r = 0; r < 4; ++r) {
        float4 o = {acc[r][0], acc[r][1], acc[r][2], acc[r][3]};
        *(float4*)&gp[(size_t)(rowg * 4 + r) * 512 + jb + lane16 * 4] = o;
    }
}

// ---------------- per step: e[n][l] = sum_h tanh(hlWa + hUa + ba) * va ----------------
__global__ void k_att_e(const float* __restrict__ hlwa, const float* __restrict__ hua_part,
                        const float* __restrict__ ba, const float* __restrict__ va,
                        float* __restrict__ e_ws) {
    int n = blockIdx.x >> 2, q = blockIdx.x & 3;
    int tid = threadIdx.x;
    int wave = tid >> 6, lane = tid & 63;
    float4 ua_a = *(const float4*)&ba[lane * 4];
    float4 ua_b = *(const float4*)&ba[256 + lane * 4];
    for (int s = 0; s < 8; ++s) {
        const float* p = hua_part + (size_t)s * NB * HD + n * HD;
        float4 pa = *(const float4*)&p[lane * 4];
        float4 pb = *(const float4*)&p[256 + lane * 4];
        ua_a.x += pa.x; ua_a.y += pa.y; ua_a.z += pa.z; ua_a.w += pa.w;
        ua_b.x += pb.x; ua_b.y += pb.y; ua_b.z += pb.z; ua_b.w += pb.w;
    }
    float4 va_a = *(const float4*)&va[lane * 4];
    float4 va_b = *(const float4*)&va[256 + lane * 4];
    for (int ll = wave; ll < 49; ll += 4) {
        int l = q * 49 + ll;
        const float* base = hlwa + ((size_t)n * LL + l) * HD;
        float4 xa = *(const float4*)&base[lane * 4];
        float4 xb = *(const float4*)&base[256 + lane * 4];
        float s = 0.f;
        s = fmaf(fast_tanh(xa.x + ua_a.x), va_a.x, s);
        s = fmaf(fast_tanh(xa.y + ua_a.y), va_a.y, s);
        s = fmaf(fast_tanh(xa.z + ua_a.z), va_a.z, s);
        s = fmaf(fast_tanh(xa.w + ua_a.w), va_a.w, s);
        s = fmaf(fast_tanh(xb.x + ua_b.x), va_b.x, s);
        s = fmaf(fast_tanh(xb.y + ua_b.y), va_b.y, s);
        s = fmaf(fast_tanh(xb.z + ua_b.z), va_b.z, s);
        s = fmaf(fast_tanh(xb.w + ua_b.w), va_b.w, s);
        for (int m = 1; m < 64; m <<= 1) s += __shfl_xor(s, m, 64);
        if (lane == 0) e_ws[n * LL + l] = s;
    }
}

// ---------------- per step: softmax over L, beta gate, z = (alpha @ hl) * beta ----------------
__global__ void k_soft_z(const float* __restrict__ e_ws, const float* __restrict__ hl,
                         const float* __restrict__ h_ws, const float* __restrict__ Wb,
                         const float* __restrict__ bb, float* __restrict__ z_ws) {
    __shared__ float red[256];
    __shared__ float alpha[256];
    __shared__ float zs[512];
    __shared__ float beta_s;
    int n = blockIdx.x, tid = threadIdx.x;
    float ev = (tid < LL) ? e_ws[n * LL + tid] : -INFINITY;
    red[tid] = ev;
    __syncthreads();
    for (int s = 128; s > 0; s >>= 1) {
        if (tid < s) red[tid] = fmaxf(red[tid], red[tid + s]);
        __syncthreads();
    }
    float m = red[0];
    __syncthreads();
    float a = (tid < LL) ? fast_exp(ev - m) : 0.f;
    red[tid] = a;
    __syncthreads();
    for (int s = 128; s > 0; s >>= 1) {
        if (tid < s) red[tid] += red[tid + s];
        __syncthreads();
    }
    float sum = red[0];
    alpha[tid] = a / sum;
    __syncthreads();
    float bp = h_ws[n * HD + tid] * Wb[tid] + h_ws[n * HD + 256 + tid] * Wb[256 + tid];
    red[tid] = bp;
    __syncthreads();
    for (int s = 128; s > 0; s >>= 1) {
        if (tid < s) red[tid] += red[tid + s];
        __syncthreads();
    }
    if (tid == 0) beta_s = fast_sigmoid(red[0] + bb[0]);
    int lq = tid >> 7, ai = tid & 127;
    const float* base = hl + ((size_t)n * LL) * AD + ai * 4;
    float4 acc4 = {0.f, 0.f, 0.f, 0.f};
    int l0 = lq * 98, l1 = l0 + 98;
    for (int l = l0; l < l1; ++l) {
        float al = alpha[l];
        float4 v = *(const float4*)&base[(size_t)l * AD];
        acc4.x = fmaf(al, v.x, acc4.x);
        acc4.y = fmaf(al, v.y, acc4.y);
        acc4.z = fmaf(al, v.z, acc4.z);
        acc4.w = fmaf(al, v.w, acc4.w);
    }
    if (lq == 1) *(float4*)&zs[ai * 4] = acc4;
    __syncthreads();
    if (lq == 0) {
        float4 o = *(const float4*)&zs[ai * 4];
        float b = beta_s;
        o.x = (o.x + acc4.x) * b;
        o.y = (o.y + acc4.y) * b;
        o.z = (o.z + acc4.z) * b;
        o.w = (o.w + acc4.w) * b;
        *(float4*)&z_ws[n * AD + ai * 4] = o;
    }
}

// ---------------- per step: gates partial GEMM  X[64x1536] @ W[1536x2048], K split 8 ----------------
__global__ void k_gates(const float* __restrict__ z_ws, const float* __restrict__ emb,
                        const int* __restrict__ tok_ws, const float* __restrict__ h_ws,
                        const float* __restrict__ Wx, const float* __restrict__ Wh,
                        float* __restrict__ gates_part) {
    __shared__ __attribute__((aligned(16))) float xt[64 * 64];
    int tid = threadIdx.x;
    int lane16 = tid & 15, rowg = tid >> 4;
    int s = blockIdx.x & 7, jt = blockIdx.x >> 3;
    int jb = jt * 64;
    float acc[4][4] = {};
    for (int ch = 0; ch < 3; ++ch) {
        int kbase = s * 192 + ch * 64;
        __syncthreads();
        for (int it = 0; it < 4; ++it) {
            int nrow = (tid >> 4) + it * 16;
            int k4 = tid & 15;
            int gk = kbase + k4 * 4;
            const float* src;
            if (gk < 512)       src = &z_ws[nrow * 512 + gk];
            else if (gk < 1024) src = &emb[(size_t)tok_ws[nrow] * 512 + (gk - 512)];
            else                src = &h_ws[nrow * 512 + (gk - 1024)];
            float4 v = *(const float4*)src;
            int col = (nrow + k4 * 4) & 63;
            xt[(k4 * 4 + 0) * 64 + col] = v.x;
            xt[(k4 * 4 + 1) * 64 + col] = v.y;
            xt[(k4 * 4 + 2) * 64 + col] = v.z;
            xt[(k4 * 4 + 3) * 64 + col] = v.w;
        }
        __syncthreads();
#pragma unroll 8
        for (int kk = 0; kk < 64; ++kk) {
            int gk = kbase + kk;
            const float* wrow = (gk < 1024) ? &Wx[(size_t)gk * G4] : &Wh[(size_t)(gk - 1024) * G4];
            float4 w4 = *(const float4*)&wrow[jb + lane16 * 4];
            float4 h4 = *(const float4*)&xt[kk * 64 + ((rowg * 4 + (kk & ~3)) & 63)];
            float hv[4] = {h4.x, h4.y, h4.z, h4.w};
            float wv[4] = {w4.x, w4.y, w4.z, w4.w};
#pragma unroll
            for (int r = 0; r < 4; ++r)
#pragma unroll
                for (int j = 0; j < 4; ++j) acc[r][j] = fmaf(hv[r], wv[j], acc[r][j]);
        }
    }
    float* gp = gates_part + (size_t)s * NB * G4;
    for (int r = 0; r < 4; ++r) {
        float4 o = {acc[r][0], acc[r][1], acc[r][2], acc[r][3]};
        *(float4*)&gp[(size_t)(rowg * 4 + r) * G4 + jb + lane16 * 4] = o;
    }
}

// ---------------- per step: reduce gate partials + LSTM cell update (+ hT for logits) ----------------
__global__ void k_lstm(const float* __restrict__ gates_part, const float* __restrict__ b_lstm,
                       float* __restrict__ h_ws, float* __restrict__ c_ws,
                       float* __restrict__ hT) {
    int idx = blockIdx.x * 256 + threadIdx.x;  // 0..32767
    int n = idx >> 9, hh = idx & 511;
    float ig = b_lstm[hh], fg = b_lstm[512 + hh], gg = b_lstm[1024 + hh], og = b_lstm[1536 + hh];
    for (int s = 0; s < 8; ++s) {
        const float* gp = gates_part + (size_t)s * NB * G4 + (size_t)n * G4;
        ig += gp[hh]; fg += gp[512 + hh]; gg += gp[1024 + hh]; og += gp[1536 + hh];
    }
    float c = c_ws[idx];
    float cn = fast_sigmoid(fg) * c + fast_sigmoid(ig) * fast_tanh(gg);
    float hn = fast_sigmoid(og) * fast_tanh(cn);
    c_ws[idx] = cn;
    h_ws[idx] = hn;
    hT[hh * 64 + n] = hn;   // transposed copy for k_logits DMA staging
}

// ---------------- per step: logits = h @ Wout + bout via async-DMA LDS staging ----------------
// hT: [512 k][64 n]. Per block: 64 vocab cols x 64 batch rows, K chunks of 64,
// double-buffered global_load_lds (w tile 16KB + h tile 16KB per buffer).
__global__ void k_logits(const float* __restrict__ hT, const float* __restrict__ Wout,
                         const float* __restrict__ bout, float* __restrict__ pval,
                         int* __restrict__ pidx) {
    __shared__ __attribute__((aligned(16))) float wbuf[2][4096];  // [k_local][64 cols]
    __shared__ __attribute__((aligned(16))) float hbuf[2][4096];  // [k_local][64 rows]
    int tid = threadIdx.x;
    int lane16 = tid & 15, rowg = tid >> 4;      // col group / batch-row group
    int wv = tid >> 6, lane = tid & 63;
    int row_off = lane >> 4, col4 = lane & 15;
    int jb = blockIdx.x * 64;
    if (jb > VD - 64) jb = VD - 64;              // clamp last tile (overlap is harmless)

    // prologue: DMA chunk 0
#pragma unroll
    for (int q = 0; q < 4; ++q) {
        int r = wv * 4 + q;
        int krow = r * 4 + row_off;
        gload_lds16(&Wout[(size_t)krow * VD + jb + col4 * 4], &wbuf[0][r * 256]);
        gload_lds16(&hT[krow * 64 + col4 * 4], &hbuf[0][r * 256]);
    }

    float acc[4][4] = {};
    for (int ch = 0; ch < 8; ++ch) {
        __syncthreads();   // drains this chunk's DMA (vmcnt(0) before barrier)
        if (ch < 7) {
            int kb = (ch + 1) * 64;
            int nb = (ch + 1) & 1;
#pragma unroll
            for (int q = 0; q < 4; ++q) {
                int r = wv * 4 + q;
                int krow = kb + r * 4 + row_off;
                gload_lds16(&Wout[(size_t)krow * VD + jb + col4 * 4], &wbuf[nb][r * 256]);
                gload_lds16(&hT[krow * 64 + col4 * 4], &hbuf[nb][r * 256]);
            }
        }
        const float* wb = wbuf[ch & 1];
        const float* hb = hbuf[ch & 1];
#pragma unroll 8
        for (int kk = 0; kk < 64; ++kk) {
            float4 h4 = *(const float4*)&hb[kk * 64 + rowg * 4];
            float4 w4 = *(const float4*)&wb[kk * 64 + lane16 * 4];
            float hv[4] = {h4.x, h4.y, h4.z, h4.w};
            float wvv[4] = {w4.x, w4.y, w4.z, w4.w};
#pragma unroll
            for (int r = 0; r < 4; ++r)
#pragma unroll
                for (int j = 0; j < 4; ++j) acc[r][j] = fmaf(hv[r], wvv[j], acc[r][j]);
        }
    }

    // epilogue: bias + per-row argmax across the 16 lanes sharing rowg
    float4 b4 = *(const float4*)&bout[jb + lane16 * 4];
    float bv[4] = {b4.x, b4.y, b4.z, b4.w};
#pragma unroll
    for (int r = 0; r < 4; ++r) {
        float best = -INFINITY;
        int bi = 0x7fffffff;
#pragma unroll
        for (int j = 0; j < 4; ++j) {
            float v = acc[r][j] + bv[j];
            if (v > best) { best = v; bi = jb + lane16 * 4 + j; }
        }
        for (int m = 1; m < 16; m <<= 1) {
            float ov = __shfl_xor(best, m, 64);
            int oi = __shfl_xor(bi, m, 64);
            if (ov > best || (ov == best && oi < bi)) { best = ov; bi = oi; }
        }
        if (lane16 == 0) {
            int row = rowg * 4 + r;
            pval[row * NB5 + blockIdx.x] = best;
            pidx[row * NB5 + blockIdx.x] = bi;
        }
    }
}

// ---------------- per step: final argmax over block partials -> token ----------------
__global__ void k_argmax(const float* __restrict__ pval, const int* __restrict__ pidx,
                         int* __restrict__ tok_ws, int* __restrict__ out, int t) {
    int n = blockIdx.x, lane = threadIdx.x;
    float best = -INFINITY; int bi = 0x7fffffff;
    for (int b = lane; b < NB5; b += 64) {
        float v = pval[n * NB5 + b];
        int id = pidx[n * NB5 + b];
        if (v > best || (v == best && id < bi)) { best = v; bi = id; }
    }
    for (int m = 1; m < 64; m <<= 1) {
        float ov = __shfl_xor(best, m, 64);
        int oi = __shfl_xor(bi, m, 64);
        if (ov > best || (ov == best && oi < bi)) { best = ov; bi = oi; }
    }
    if (lane == 0) { tok_ws[n] = bi; out[n * TS + t] = bi; }
}

extern "C" void kernel_launch(void* const* d_in, const int* in_sizes, int n_in,
                              void* d_out, int out_size, void* d_ws, size_t ws_size,
                              hipStream_t stream) {
    const float* hl     = (const float*)d_in[0];
    const float* emb    = (const float*)d_in[1];
    const float* Wh0    = (const float*)d_in[2];
    const float* bh0    = (const float*)d_in[3];
    const float* Wc0    = (const float*)d_in[4];
    const float* bc0    = (const float*)d_in[5];
    const float* Wa     = (const float*)d_in[6];
    const float* Ua     = (const float*)d_in[7];
    const float* ba     = (const float*)d_in[8];
    const float* va     = (const float*)d_in[9];
    const float* Wb     = (const float*)d_in[10];
    const float* bb     = (const float*)d_in[11];
    const float* Wx     = (const float*)d_in[12];
    const float* Wh     = (const float*)d_in[13];
    const float* b_lstm = (const float*)d_in[14];
    const float* Wout   = (const float*)d_in[15];
    const float* bout   = (const float*)d_in[16];

    float* ws         = (float*)d_ws;
    float* hlwa       = ws;                          // 6422528
    float* h_ws       = ws + 6422528;                // 32768
    float* c_ws       = h_ws + 32768;                // 32768
    float* z_ws       = c_ws + 32768;                // 32768
    float* e_ws       = z_ws + 32768;                // 12544
    int*   tok_ws     = (int*)(e_ws + 12544);        // 64
    float* hua_part   = e_ws + 12544 + 64;           // 8*64*512 = 262144
    float* gates_part = hua_part + 262144;           // 8*64*2048 = 1048576
    float* pval       = gates_part + 1048576;        // 64*469
    int*   pidx       = (int*)(pval + 64 * NB5);     // 64*469
    float* hT         = pval + 2 * 64 * NB5;         // 512*64 = 32768
    int*   out        = (int*)d_out;

    k_init<<<64, 256, 0, stream>>>(hl, Wh0, bh0, Wc0, bc0, h_ws, c_ws, tok_ws);
    k_hlwa<<<dim3(196, 8), 256, 0, stream>>>(hl, Wa, hlwa);
    for (int t = 0; t < TS; ++t) {
        k_hua<<<64, 256, 0, stream>>>(h_ws, Ua, hua_part);
        k_att_e<<<256, 256, 0, stream>>>(hlwa, hua_part, ba, va, e_ws);
        k_soft_z<<<64, 256, 0, stream>>>(e_ws, hl, h_ws, Wb, bb, z_ws);
        k_gates<<<256, 256, 0, stream>>>(z_ws, emb, tok_ws, h_ws, Wx, Wh, gates_part);
        k_lstm<<<128, 256, 0, stream>>>(gates_part, b_lstm, h_ws, c_ws, hT);
        k_logits<<<NB5, 256, 0, stream>>>(hT, Wout, bout, pval, pidx);
        k_argmax<<<64, 64, 0, stream>>>(pval, pidx, tok_ws, out, t);
    }
}